// Round 7
// baseline (377.084 us; speedup 1.0000x reference)
//
#include <hip/hip_runtime.h>
#include <hip/hip_cooperative_groups.h>

namespace cg = cooperative_groups;

#define SQ 2048
#define DM 512
#define NH 8
#define NZ 2            // KV split: 16 tiles of 64 each

typedef __bf16 bf16x8 __attribute__((ext_vector_type(8)));
typedef float f32x4 __attribute__((ext_vector_type(4)));
typedef unsigned short us8 __attribute__((ext_vector_type(8)));

__device__ __forceinline__ unsigned short f2bf(float f) {
    unsigned u = __builtin_bit_cast(unsigned, f);
    u += 0x7fffu + ((u >> 16) & 1u);     // round-to-nearest-even
    return (unsigned short)(u >> 16);
}
__device__ __forceinline__ unsigned short f2bf_trunc(float f) {
    return (unsigned short)(__builtin_bit_cast(unsigned, f) >> 16);
}

// ======================= phase 0: conversions (512 blocks) =======================
__device__ __forceinline__ void phase0(
    int b, int tid, unsigned char* smem,
    const float* emb, const float* Kin, const float* Vin,
    const float* Wq,  const float* Wk,  const float* Wv,  const float* Wo,
    unsigned short* xe, unsigned short* xk, unsigned short* xv,
    unsigned short* Wt, unsigned short* Wot)
{
    float* ld = (float*)smem;
    float4* ld4 = (float4*)smem;
    const int rr = tid >> 4, c4 = tid & 15;

    if (b < 192) {
        // Wq/Wk/Wv 64k x 64n tile transpose -> Wt[(p*8+h)][64 n][512 k]
        const int idx = b >> 3, kt = b & 7;
        const int p = idx >> 3, h = idx & 7;
        const float* src = ((p == 0) ? Wq : (p == 1) ? Wk : Wv)
                         + (size_t)h * 512 * 64 + (size_t)kt * 64 * 64;
        unsigned short* dst = Wt + (size_t)idx * 64 * 512 + kt * 64;
        #pragma unroll
        for (int it = 0; it < 4; it++) {
            int r = rr + 16 * it;
            ld4[r * 17 + c4] = reinterpret_cast<const float4*>(src + (size_t)r * 64)[c4];
        }
        __syncthreads();
        #pragma unroll
        for (int it = 0; it < 2; it++) {
            int slot = tid + it * 256;
            int n = slot >> 3, g = slot & 7;
            us8 o;
            #pragma unroll
            for (int i = 0; i < 8; i++)
                o[i] = f2bf(ld[(g * 8 + i) * 68 + n]);
            *reinterpret_cast<us8*>(dst + (size_t)n * 512 + g * 8) = o;
        }
    } else if (b < 256) {
        // Wo 64x64 tile transpose -> Wot [512 n][512 k]
        const int ti = b - 192;
        const int kt = ti >> 3, nt = ti & 7;
        const float* src = Wo + (size_t)kt * 64 * 512 + nt * 64;
        #pragma unroll
        for (int it = 0; it < 4; it++) {
            int r = rr + 16 * it;
            ld4[r * 17 + c4] = reinterpret_cast<const float4*>(src + (size_t)r * 512)[c4];
        }
        __syncthreads();
        #pragma unroll
        for (int it = 0; it < 2; it++) {
            int slot = tid + it * 256;
            int n = slot >> 3, g = slot & 7;
            us8 o;
            #pragma unroll
            for (int i = 0; i < 8; i++)
                o[i] = f2bf(ld[(g * 8 + i) * 68 + n]);
            *reinterpret_cast<us8*>(Wot + (size_t)(nt * 64 + n) * 512 + kt * 64 + g * 8) = o;
        }
    } else {
        // X (emb/K/V) -> bf16: 256 units x 24 rows
        const int u = b - 256;
        #pragma unroll
        for (int k = 0; k < 6; k++) {
            int o = tid + k * 256;
            int rl = o >> 6, oc = o & 63;
            int g = u * 24 + rl;
            int m = g >> 11, r = g & 2047;
            const float* src = (m == 0) ? emb : (m == 1) ? Kin : Vin;
            unsigned short* dst = (m == 0) ? xe : (m == 1) ? xk : xv;
            const float4* s4 = reinterpret_cast<const float4*>(src + (size_t)r * 512 + oc * 8);
            float4 f0 = s4[0], f1 = s4[1];
            us8 oo;
            oo[0] = f2bf(f0.x); oo[1] = f2bf(f0.y); oo[2] = f2bf(f0.z); oo[3] = f2bf(f0.w);
            oo[4] = f2bf(f1.x); oo[5] = f2bf(f1.y); oo[6] = f2bf(f1.z); oo[7] = f2bf(f1.w);
            *reinterpret_cast<us8*>(dst + (size_t)r * 512 + oc * 8) = oo;
        }
    }
}

// ======================= phase 1: QKV projections (384 blocks, 128-row tiles) ===
__device__ __forceinline__ void phase1(
    int b, int tid, unsigned char* smem,
    const unsigned short* xe, const unsigned short* xk, const unsigned short* xv,
    const unsigned short* Wt,
    const float* bq, const float* bk, const float* bv,
    unsigned short* qbf, unsigned short* kbf, unsigned short* vbf)
{
    const int p = b >> 7, rem = b & 127;
    const int h = rem >> 4, s0 = (rem & 15) * 128;
    const unsigned short* X = (p == 0) ? xe : (p == 1) ? xk : xv;
    const unsigned short* W = Wt + (size_t)(p * 8 + h) * 64 * 512;
    const float* B = ((p == 0) ? bq : (p == 1) ? bk : bv) + h * 64;

    unsigned short* As = (unsigned short*)smem;              // 128 x 72
    unsigned short* Bs = (unsigned short*)(smem + 18432);    // 64 x 72

    const int w = tid >> 6, lane = tid & 63, cl = lane & 15, q4 = lane >> 4;

    // prefetch chunk 0
    float4 ar[4], br[2];
    #pragma unroll
    for (int it = 0; it < 4; it++) {
        int slot = tid + it * 256; int r = slot >> 3, g = slot & 7;
        ar[it] = *reinterpret_cast<const float4*>(&X[(size_t)(s0 + r) * 512 + g * 8]);
    }
    #pragma unroll
    for (int it = 0; it < 2; it++) {
        int slot = tid + it * 256; int n = slot >> 3, g = slot & 7;
        br[it] = *reinterpret_cast<const float4*>(&W[(size_t)n * 512 + g * 8]);
    }

    f32x4 acc[2][4] = {};
    for (int c = 0; c < 8; c++) {
        if (c) __syncthreads();
        #pragma unroll
        for (int it = 0; it < 4; it++) {
            int slot = tid + it * 256; int r = slot >> 3, g = slot & 7;
            *reinterpret_cast<float4*>(&As[r * 72 + g * 8]) = ar[it];
        }
        #pragma unroll
        for (int it = 0; it < 2; it++) {
            int slot = tid + it * 256; int n = slot >> 3, g = slot & 7;
            *reinterpret_cast<float4*>(&Bs[n * 72 + g * 8]) = br[it];
        }
        __syncthreads();
        if (c + 1 < 8) {
            #pragma unroll
            for (int it = 0; it < 4; it++) {
                int slot = tid + it * 256; int r = slot >> 3, g = slot & 7;
                ar[it] = *reinterpret_cast<const float4*>(
                    &X[(size_t)(s0 + r) * 512 + (c + 1) * 64 + g * 8]);
            }
            #pragma unroll
            for (int it = 0; it < 2; it++) {
                int slot = tid + it * 256; int n = slot >> 3, g = slot & 7;
                br[it] = *reinterpret_cast<const float4*>(
                    &W[(size_t)n * 512 + (c + 1) * 64 + g * 8]);
            }
        }
        bf16x8 a[2][2];
        #pragma unroll
        for (int mi = 0; mi < 2; mi++)
            #pragma unroll
            for (int ch = 0; ch < 2; ch++)
                a[mi][ch] = *reinterpret_cast<const bf16x8*>(
                    &As[(32 * w + 16 * mi + cl) * 72 + ch * 32 + q4 * 8]);
        #pragma unroll
        for (int nn = 0; nn < 4; nn++) {
            #pragma unroll
            for (int ch = 0; ch < 2; ch++) {
                bf16x8 bfr = *reinterpret_cast<const bf16x8*>(
                    &Bs[(16 * nn + cl) * 72 + ch * 32 + q4 * 8]);
                #pragma unroll
                for (int mi = 0; mi < 2; mi++)
                    acc[mi][nn] = __builtin_amdgcn_mfma_f32_16x16x32_bf16(
                        a[mi][ch], bfr, acc[mi][nn], 0, 0, 0);
            }
        }
    }

    #pragma unroll
    for (int mi = 0; mi < 2; mi++) {
        const int row0 = s0 + 32 * w + 16 * mi + q4 * 4;
        if (p == 0) {
            #pragma unroll
            for (int nn = 0; nn < 4; nn++) {
                int col = 16 * nn + cl;
                float bb = B[col];
                #pragma unroll
                for (int r = 0; r < 4; r++)
                    qbf[((size_t)h * SQ + row0 + r) * 64 + col] =
                        f2bf((acc[mi][nn][r] + bb) * 0.125f);
            }
        } else if (p == 1) {
            #pragma unroll
            for (int nn = 0; nn < 4; nn++) {
                int col = 16 * nn + cl;
                float bb = B[col];
                #pragma unroll
                for (int r = 0; r < 4; r++)
                    kbf[((size_t)h * SQ + row0 + r) * 64 + col] =
                        f2bf(acc[mi][nn][r] + bb);
            }
        } else {
            #pragma unroll
            for (int nn = 0; nn < 4; nn++) {
                int col = 16 * nn + cl;
                float bb = B[col];
                ushort4 o;
                o.x = f2bf(acc[mi][nn][0] + bb);
                o.y = f2bf(acc[mi][nn][1] + bb);
                o.z = f2bf(acc[mi][nn][2] + bb);
                o.w = f2bf(acc[mi][nn][3] + bb);
                *reinterpret_cast<ushort4*>(vbf + ((size_t)h * 64 + col) * SQ + row0) = o;
            }
        }
    }
}

// ======================= phase 2: attention, KV-split x2 (512 blocks) ===========
__device__ __forceinline__ void phase2(
    int b, int tid, unsigned char* smem,
    const unsigned short* qbf, const unsigned short* kbf, const unsigned short* vbf,
    float* Opart, float* lpart)
{
    const int h = b & 7;
    const int qd = b >> 3;                    // 0..63
    const int z = qd & 1, sbk = qd >> 1;      // z-split, s-block 0..31
    const int s0 = sbk * 64;
    const int t0 = z * 16;
    const int NT = 16;

    unsigned short* Ks = (unsigned short*)smem;               // 64 x 72
    unsigned short* Vs = (unsigned short*)(smem + 9216);      // 64 x 72
    unsigned short* Ps = (unsigned short*)(smem + 18432) + (tid >> 6) * 1152;

    const int w = tid >> 6, lane = tid & 63, cl = lane & 15, q4 = lane >> 4;
    const int sr = tid >> 3, sg = tid & 7;

    bf16x8 aq0 = *reinterpret_cast<const bf16x8*>(
        &qbf[((size_t)h * SQ + s0 + 16 * w + cl) * 64 + q4 * 8]);
    bf16x8 aq1 = *reinterpret_cast<const bf16x8*>(
        &qbf[((size_t)h * SQ + s0 + 16 * w + cl) * 64 + 32 + q4 * 8]);

    // prefetch tile 0
    float4 kr[2], vr[2];
    #pragma unroll
    for (int it = 0; it < 2; it++) {
        int r = sr + 32 * it;
        kr[it] = *reinterpret_cast<const float4*>(
            &kbf[((size_t)h * SQ + t0 * 64 + r) * 64 + sg * 8]);
        vr[it] = *reinterpret_cast<const float4*>(
            &vbf[((size_t)h * 64 + r) * SQ + t0 * 64 + sg * 8]);
    }

    f32x4 o_acc[4] = {};
    float lsum[4] = {};

    for (int tl = 0; tl < NT; tl++) {
        if (tl) __syncthreads();
        #pragma unroll
        for (int it = 0; it < 2; it++) {
            int r = sr + 32 * it;
            *reinterpret_cast<float4*>(&Ks[r * 72 + sg * 8]) = kr[it];
            *reinterpret_cast<float4*>(&Vs[r * 72 + sg * 8]) = vr[it];
        }
        __syncthreads();
        if (tl + 1 < NT) {
            #pragma unroll
            for (int it = 0; it < 2; it++) {
                int r = sr + 32 * it;
                kr[it] = *reinterpret_cast<const float4*>(
                    &kbf[((size_t)h * SQ + (t0 + tl + 1) * 64 + r) * 64 + sg * 8]);
                vr[it] = *reinterpret_cast<const float4*>(
                    &vbf[((size_t)h * 64 + r) * SQ + (t0 + tl + 1) * 64 + sg * 8]);
            }
        }

        f32x4 s_acc[4] = {};
        #pragma unroll
        for (int nn = 0; nn < 4; nn++) {
            bf16x8 b0 = *reinterpret_cast<const bf16x8*>(&Ks[(16 * nn + cl) * 72 + q4 * 8]);
            bf16x8 b1 = *reinterpret_cast<const bf16x8*>(&Ks[(16 * nn + cl) * 72 + 32 + q4 * 8]);
            s_acc[nn] = __builtin_amdgcn_mfma_f32_16x16x32_bf16(aq0, b0, s_acc[nn], 0, 0, 0);
            s_acc[nn] = __builtin_amdgcn_mfma_f32_16x16x32_bf16(aq1, b1, s_acc[nn], 0, 0, 0);
        }

        #pragma unroll
        for (int r = 0; r < 4; r++) {
            #pragma unroll
            for (int nn = 0; nn < 4; nn++) {
                float pv = __expf(s_acc[nn][r]);
                lsum[r] += pv;
                Ps[(q4 * 4 + r) * 72 + 16 * nn + cl] = f2bf_trunc(pv);
            }
        }
        bf16x8 ap0 = *reinterpret_cast<const bf16x8*>(&Ps[cl * 72 + q4 * 8]);
        bf16x8 ap1 = *reinterpret_cast<const bf16x8*>(&Ps[cl * 72 + 32 + q4 * 8]);

        #pragma unroll
        for (int nn = 0; nn < 4; nn++) {
            bf16x8 b0 = *reinterpret_cast<const bf16x8*>(&Vs[(16 * nn + cl) * 72 + q4 * 8]);
            bf16x8 b1 = *reinterpret_cast<const bf16x8*>(&Vs[(16 * nn + cl) * 72 + 32 + q4 * 8]);
            o_acc[nn] = __builtin_amdgcn_mfma_f32_16x16x32_bf16(ap0, b0, o_acc[nn], 0, 0, 0);
            o_acc[nn] = __builtin_amdgcn_mfma_f32_16x16x32_bf16(ap1, b1, o_acc[nn], 0, 0, 0);
        }
    }

    #pragma unroll
    for (int r = 0; r < 4; r++) {
        float v = lsum[r];
        #pragma unroll
        for (int off = 1; off < 16; off <<= 1) v += __shfl_xor(v, off);
        lsum[r] = v;
    }

    const size_t zb = (size_t)(z * 8 + h);
    if (cl == 0) {
        #pragma unroll
        for (int r = 0; r < 4; r++)
            lpart[zb * SQ + s0 + 16 * w + q4 * 4 + r] = lsum[r];
    }
    #pragma unroll
    for (int nn = 0; nn < 4; nn++)
        #pragma unroll
        for (int r = 0; r < 4; r++)
            Opart[(zb * SQ + s0 + 16 * w + q4 * 4 + r) * 64 + 16 * nn + cl] = o_acc[nn][r];
}

// ======================= phase 3: combine + output projection (256 blocks) ======
__device__ __forceinline__ void phase3(
    int b, int tid, unsigned char* smem,
    const float* Opart, const float* lpart,
    const unsigned short* Wot, const float* bo, float* out)
{
    const int s0 = (b >> 3) * 64, n0 = (b & 7) * 64;
    unsigned short* As = (unsigned short*)smem;
    unsigned short* Bs = (unsigned short*)(smem + 9216);
    float* invL = (float*)(smem + 18432);     // 512 floats

    const int w = tid >> 6, lane = tid & 63, cl = lane & 15, q4 = lane >> 4;
    const int sr = tid >> 3, sg = tid & 7;

    #pragma unroll
    for (int k = 0; k < 2; k++) {
        int idx = tid * 2 + k;
        int hh = idx >> 6, ss = idx & 63;
        float l = 0.f;
        #pragma unroll
        for (int z = 0; z < NZ; z++)
            l += lpart[(size_t)(z * 8 + hh) * SQ + s0 + ss];
        invL[idx] = 1.0f / l;
    }
    __syncthreads();

    f32x4 acc[4] = {};
    for (int c = 0; c < 8; c++) {
        if (c) __syncthreads();
        #pragma unroll
        for (int it = 0; it < 2; it++) {
            int r = sr + 32 * it;
            float o[8] = {};
            #pragma unroll
            for (int z = 0; z < NZ; z++) {
                const float4* pp = reinterpret_cast<const float4*>(
                    &Opart[((size_t)(z * 8 + c) * SQ + s0 + r) * 64 + sg * 8]);
                float4 a = pp[0], b4 = pp[1];
                o[0] += a.x;  o[1] += a.y;  o[2] += a.z;  o[3] += a.w;
                o[4] += b4.x; o[5] += b4.y; o[6] += b4.z; o[7] += b4.w;
            }
            float il = invL[c * 64 + r];
            us8 pk;
            #pragma unroll
            for (int i = 0; i < 8; i++) pk[i] = f2bf(o[i] * il);
            *reinterpret_cast<us8*>(&As[r * 72 + sg * 8]) = pk;
            *reinterpret_cast<float4*>(&Bs[r * 72 + sg * 8]) =
                *reinterpret_cast<const float4*>(&Wot[(size_t)(n0 + r) * 512 + c * 64 + sg * 8]);
        }
        __syncthreads();

        bf16x8 a0 = *reinterpret_cast<const bf16x8*>(&As[(16 * w + cl) * 72 + q4 * 8]);
        bf16x8 a1 = *reinterpret_cast<const bf16x8*>(&As[(16 * w + cl) * 72 + 32 + q4 * 8]);
        #pragma unroll
        for (int nn = 0; nn < 4; nn++) {
            bf16x8 b0 = *reinterpret_cast<const bf16x8*>(&Bs[(16 * nn + cl) * 72 + q4 * 8]);
            bf16x8 b1 = *reinterpret_cast<const bf16x8*>(&Bs[(16 * nn + cl) * 72 + 32 + q4 * 8]);
            acc[nn] = __builtin_amdgcn_mfma_f32_16x16x32_bf16(a0, b0, acc[nn], 0, 0, 0);
            acc[nn] = __builtin_amdgcn_mfma_f32_16x16x32_bf16(a1, b1, acc[nn], 0, 0, 0);
        }
    }

    #pragma unroll
    for (int nn = 0; nn < 4; nn++) {
        int col = n0 + 16 * nn + cl;
        float bb = bo[col];
        #pragma unroll
        for (int r = 0; r < 4; r++)
            out[(size_t)(s0 + 16 * w + q4 * 4 + r) * DM + col] = acc[nn][r] + bb;
    }
}

// ======================= cooperative fused kernel (512 blocks) ==================
__global__ void __launch_bounds__(256, 2) fused_all(
    const float* emb, const float* Kin, const float* Vin,
    const float* Wq,  const float* Wk,  const float* Wv,  const float* Wo,
    const float* bq,  const float* bk,  const float* bv,  const float* bo,
    unsigned short* xe, unsigned short* xk, unsigned short* xv,
    unsigned short* Wt, unsigned short* Wot,
    unsigned short* qbf, unsigned short* kbf, unsigned short* vbf,
    float* Opart, float* lpart, float* out)
{
    __shared__ __align__(16) unsigned char smem[27648];
    const int b = blockIdx.x, tid = threadIdx.x;
    cg::grid_group grid = cg::this_grid();

    phase0(b, tid, smem, emb, Kin, Vin, Wq, Wk, Wv, Wo, xe, xk, xv, Wt, Wot);
    grid.sync();
    if (b < 384) phase1(b, tid, smem, xe, xk, xv, Wt, bq, bk, bv, qbf, kbf, vbf);
    grid.sync();
    phase2(b, tid, smem, qbf, kbf, vbf, Opart, lpart);
    grid.sync();
    if (b < 256) phase3(b, tid, smem, Opart, lpart, Wot, bo, out);
}

// ======================= fallback standalone kernels ============================
__global__ __launch_bounds__(256) void k_phase0(
    const float* emb, const float* Kin, const float* Vin,
    const float* Wq, const float* Wk, const float* Wv, const float* Wo,
    unsigned short* xe, unsigned short* xk, unsigned short* xv,
    unsigned short* Wt, unsigned short* Wot)
{
    __shared__ __align__(16) unsigned char smem[17408];
    phase0(blockIdx.x, threadIdx.x, smem, emb, Kin, Vin, Wq, Wk, Wv, Wo,
           xe, xk, xv, Wt, Wot);
}

__global__ __launch_bounds__(256) void k_phase1(
    const unsigned short* xe, const unsigned short* xk, const unsigned short* xv,
    const unsigned short* Wt,
    const float* bq, const float* bk, const float* bv,
    unsigned short* qbf, unsigned short* kbf, unsigned short* vbf)
{
    __shared__ __align__(16) unsigned char smem[27648];
    phase1(blockIdx.x, threadIdx.x, smem, xe, xk, xv, Wt, bq, bk, bv, qbf, kbf, vbf);
}

__global__ __launch_bounds__(256) void k_phase2(
    const unsigned short* qbf, const unsigned short* kbf, const unsigned short* vbf,
    float* Opart, float* lpart)
{
    __shared__ __align__(16) unsigned char smem[27648];
    phase2(blockIdx.x, threadIdx.x, smem, qbf, kbf, vbf, Opart, lpart);
}

__global__ __launch_bounds__(256) void k_phase3(
    const float* Opart, const float* lpart,
    const unsigned short* Wot, const float* bo, float* out)
{
    __shared__ __align__(16) unsigned char smem[20480];
    phase3(blockIdx.x, threadIdx.x, smem, Opart, lpart, Wot, bo, out);
}

extern "C" void kernel_launch(void* const* d_in, const int* in_sizes, int n_in,
                              void* d_out, int out_size, void* d_ws, size_t ws_size,
                              hipStream_t stream) {
    const float* emb = (const float*)d_in[0];
    const float* Kin = (const float*)d_in[1];
    const float* Vin = (const float*)d_in[2];
    const float* Wq  = (const float*)d_in[3];
    const float* bq  = (const float*)d_in[4];
    const float* Wk  = (const float*)d_in[5];
    const float* bk  = (const float*)d_in[6];
    const float* Wv  = (const float*)d_in[7];
    const float* bv  = (const float*)d_in[8];
    const float* Wo  = (const float*)d_in[9];
    const float* bo  = (const float*)d_in[10];
    float* out = (float*)d_out;

    unsigned short* p = (unsigned short*)d_ws;
    unsigned short* xe  = p; p += (size_t)SQ * DM;
    unsigned short* xk  = p; p += (size_t)SQ * DM;
    unsigned short* xv  = p; p += (size_t)SQ * DM;
    unsigned short* Wt  = p; p += (size_t)24 * 64 * 512;
    unsigned short* Wot = p; p += (size_t)512 * 512;
    unsigned short* qbf = p; p += (size_t)NH * SQ * 64;
    unsigned short* kbf = p; p += (size_t)NH * SQ * 64;
    unsigned short* vbf = p; p += (size_t)NH * SQ * 64;
    float* Opart = (float*)p;                               // 8 MB
    float* lpart = Opart + (size_t)NZ * NH * SQ * 64;       // 128 KB

    void* args[] = {
        (void*)&emb, (void*)&Kin, (void*)&Vin,
        (void*)&Wq,  (void*)&Wk,  (void*)&Wv,  (void*)&Wo,
        (void*)&bq,  (void*)&bk,  (void*)&bv,  (void*)&bo,
        (void*)&xe,  (void*)&xk,  (void*)&xv,
        (void*)&Wt,  (void*)&Wot,
        (void*)&qbf, (void*)&kbf, (void*)&vbf,
        (void*)&Opart, (void*)&lpart, (void*)&out,
    };
    hipError_t e = hipLaunchCooperativeKernel((void*)fused_all, dim3(512), dim3(256),
                                              args, 0, stream);
    if (e != hipSuccess) {
        // deterministic fallback: identical math as 4 separate launches
        (void)hipGetLastError();
        k_phase0<<<512, 256, 0, stream>>>(emb, Kin, Vin, Wq, Wk, Wv, Wo,
                                          xe, xk, xv, Wt, Wot);
        k_phase1<<<384, 256, 0, stream>>>(xe, xk, xv, Wt, bq, bk, bv, qbf, kbf, vbf);
        k_phase2<<<512, 256, 0, stream>>>(qbf, kbf, vbf, Opart, lpart);
        k_phase3<<<256, 256, 0, stream>>>(Opart, lpart, Wot, bo, out);
    }
}

// Round 8
// 130.268 us; speedup vs baseline: 2.8947x; 2.8947x over previous
//
#include <hip/hip_runtime.h>

#define SQ 2048
#define DM 512
#define NH 8
#define NSPLIT 4

typedef __bf16 bf16x8 __attribute__((ext_vector_type(8)));
typedef float f32x4 __attribute__((ext_vector_type(4)));
typedef unsigned short us8 __attribute__((ext_vector_type(8)));

__device__ __forceinline__ unsigned short f2bf(float f) {
    unsigned u = __builtin_bit_cast(unsigned, f);
    u += 0x7fffu + ((u >> 16) & 1u);     // round-to-nearest-even
    return (unsigned short)(u >> 16);
}
__device__ __forceinline__ unsigned short f2bf_trunc(float f) {
    return (unsigned short)(__builtin_bit_cast(unsigned, f) >> 16);
}

// ---------------------------------------------------------------------------
// Kernel 0: all bf16 conversions, fully parallel + coalesced (R4 version).
//  b [0,1536):    emb/K/V -> xe/xk/xv (straight copy-convert)
//  b [1536,1728): Wq/Wk/Wv 64k x 64n tile transpose -> Wt[(p*8+h)][64 n][512 k]
//  b [1728,1792): Wo 64x64 tile transpose -> Wot [512 n][512 k]
// ---------------------------------------------------------------------------
__global__ __launch_bounds__(256) void convert_all(
    const float* __restrict__ emb, const float* __restrict__ Kin, const float* __restrict__ Vin,
    const float* __restrict__ Wq,  const float* __restrict__ Wk,  const float* __restrict__ Wv,
    const float* __restrict__ Wo,
    unsigned short* __restrict__ xe, unsigned short* __restrict__ xk, unsigned short* __restrict__ xv,
    unsigned short* __restrict__ Wt, unsigned short* __restrict__ Wot)
{
    const int b = blockIdx.x, tid = threadIdx.x;
    __shared__ float ld[64 * 68];
    float4* ld4 = reinterpret_cast<float4*>(ld);

    if (b < 1536) {
        const int m = b >> 9;
        const float* src = (m == 0) ? emb : (m == 1) ? Kin : Vin;
        unsigned short* dst = (m == 0) ? xe : (m == 1) ? xk : xv;
        const int oct = (b & 511) * 256 + tid;
        const float4* s4 = reinterpret_cast<const float4*>(src + (size_t)oct * 8);
        float4 f0 = s4[0], f1 = s4[1];
        us8 o;
        o[0] = f2bf(f0.x); o[1] = f2bf(f0.y); o[2] = f2bf(f0.z); o[3] = f2bf(f0.w);
        o[4] = f2bf(f1.x); o[5] = f2bf(f1.y); o[6] = f2bf(f1.z); o[7] = f2bf(f1.w);
        *reinterpret_cast<us8*>(dst + (size_t)oct * 8) = o;
    } else if (b < 1728) {
        const int wi = b - 1536;             // 0..191
        const int idx = wi >> 3;             // p*8+h
        const int kt = wi & 7;               // k-tile of 64
        const int p = idx >> 3, h = idx & 7;
        const float* src = ((p == 0) ? Wq : (p == 1) ? Wk : Wv)
                         + (size_t)h * 512 * 64 + (size_t)kt * 64 * 64;
        unsigned short* dst = Wt + (size_t)idx * 64 * 512 + kt * 64;
        const int rr = tid >> 4, c4 = tid & 15;
        #pragma unroll
        for (int it = 0; it < 4; it++) {
            int r = rr + 16 * it;            // k-row in tile
            ld4[r * 17 + c4] = reinterpret_cast<const float4*>(src + (size_t)r * 64)[c4];
        }
        __syncthreads();
        #pragma unroll
        for (int it = 0; it < 2; it++) {
            int slot = tid + it * 256;
            int n = slot >> 3, g = slot & 7;
            us8 o;
            #pragma unroll
            for (int i = 0; i < 8; i++)
                o[i] = f2bf(ld[(g * 8 + i) * 68 + n]);
            *reinterpret_cast<us8*>(dst + (size_t)n * 512 + g * 8) = o;
        }
    } else {
        const int ti = b - 1728;             // 0..63
        const int kt = ti >> 3, nt = ti & 7;
        const float* src = Wo + (size_t)kt * 64 * 512 + nt * 64;
        const int rr = tid >> 4, c4 = tid & 15;
        #pragma unroll
        for (int it = 0; it < 4; it++) {
            int r = rr + 16 * it;
            ld4[r * 17 + c4] = reinterpret_cast<const float4*>(src + (size_t)r * 512)[c4];
        }
        __syncthreads();
        #pragma unroll
        for (int it = 0; it < 2; it++) {
            int slot = tid + it * 256;
            int n = slot >> 3, g = slot & 7;
            us8 o;
            #pragma unroll
            for (int i = 0; i < 8; i++)
                o[i] = f2bf(ld[(g * 8 + i) * 68 + n]);
            *reinterpret_cast<us8*>(Wot + (size_t)(nt * 64 + n) * 512 + kt * 64 + g * 8) = o;
        }
    }
}

// ---------------------------------------------------------------------------
// Kernel 1: QKV projections via bf16 MFMA, double-buffered LDS, ONE barrier
// per K-chunk (R4 version). grid (32, 8, 3), block 256 (4 waves).
// ---------------------------------------------------------------------------
__global__ __launch_bounds__(256) void qkv_mfma(
    const unsigned short* __restrict__ xe, const unsigned short* __restrict__ xk,
    const unsigned short* __restrict__ xv, const unsigned short* __restrict__ Wt,
    const float* __restrict__ bq, const float* __restrict__ bk, const float* __restrict__ bv,
    unsigned short* __restrict__ qo, unsigned short* __restrict__ ko, unsigned short* __restrict__ vo)
{
    const int p = blockIdx.z, h = blockIdx.y, s0 = blockIdx.x * 64;
    const unsigned short* X = (p == 0) ? xe : (p == 1) ? xk : xv;
    const unsigned short* W = Wt + (size_t)(p * 8 + h) * 64 * 512;
    const float* B = ((p == 0) ? bq : (p == 1) ? bk : bv) + h * 64;

    const int tid = threadIdx.x;
    const int w = tid >> 6, lane = tid & 63, cl = lane & 15, q4 = lane >> 4;
    const int sr = tid >> 3, sg = tid & 7;

    __shared__ unsigned short As[2][64 * 72];
    __shared__ unsigned short Bs[2][64 * 72];

    #pragma unroll
    for (int it = 0; it < 2; it++) {
        int r = sr + 32 * it;
        *reinterpret_cast<float4*>(&As[0][r * 72 + sg * 8]) =
            *reinterpret_cast<const float4*>(&X[(size_t)(s0 + r) * 512 + sg * 8]);
        *reinterpret_cast<float4*>(&Bs[0][r * 72 + sg * 8]) =
            *reinterpret_cast<const float4*>(&W[(size_t)r * 512 + sg * 8]);
    }

    f32x4 acc[4] = {};

    for (int c = 0; c < 8; c++) {
        __syncthreads();
        const int buf = c & 1;
        const bool more = (c + 1 < 8);
        float4 ar[2], br[2];
        if (more) {
            #pragma unroll
            for (int it = 0; it < 2; it++) {
                int r = sr + 32 * it;
                ar[it] = *reinterpret_cast<const float4*>(
                    &X[(size_t)(s0 + r) * 512 + (c + 1) * 64 + sg * 8]);
                br[it] = *reinterpret_cast<const float4*>(
                    &W[(size_t)r * 512 + (c + 1) * 64 + sg * 8]);
            }
        }

        bf16x8 a0 = *reinterpret_cast<const bf16x8*>(&As[buf][(16 * w + cl) * 72 + q4 * 8]);
        bf16x8 a1 = *reinterpret_cast<const bf16x8*>(&As[buf][(16 * w + cl) * 72 + 32 + q4 * 8]);
        #pragma unroll
        for (int nn = 0; nn < 4; nn++) {
            bf16x8 b0 = *reinterpret_cast<const bf16x8*>(&Bs[buf][(16 * nn + cl) * 72 + q4 * 8]);
            bf16x8 b1 = *reinterpret_cast<const bf16x8*>(&Bs[buf][(16 * nn + cl) * 72 + 32 + q4 * 8]);
            acc[nn] = __builtin_amdgcn_mfma_f32_16x16x32_bf16(a0, b0, acc[nn], 0, 0, 0);
            acc[nn] = __builtin_amdgcn_mfma_f32_16x16x32_bf16(a1, b1, acc[nn], 0, 0, 0);
        }

        if (more) {
            const int nbuf = buf ^ 1;
            #pragma unroll
            for (int it = 0; it < 2; it++) {
                int r = sr + 32 * it;
                *reinterpret_cast<float4*>(&As[nbuf][r * 72 + sg * 8]) = ar[it];
                *reinterpret_cast<float4*>(&Bs[nbuf][r * 72 + sg * 8]) = br[it];
            }
        }
    }

    if (p == 0) {
        #pragma unroll
        for (int nn = 0; nn < 4; nn++) {
            int col = 16 * nn + cl;
            float bb = B[col];
            #pragma unroll
            for (int r = 0; r < 4; r++)
                qo[((size_t)h * SQ + s0 + 16 * w + q4 * 4 + r) * 64 + col] =
                    f2bf((acc[nn][r] + bb) * 0.125f);
        }
    } else if (p == 1) {
        #pragma unroll
        for (int nn = 0; nn < 4; nn++) {
            int col = 16 * nn + cl;
            float bb = B[col];
            #pragma unroll
            for (int r = 0; r < 4; r++)
                ko[((size_t)h * SQ + s0 + 16 * w + q4 * 4 + r) * 64 + col] =
                    f2bf(acc[nn][r] + bb);
        }
    } else {
        #pragma unroll
        for (int nn = 0; nn < 4; nn++) {
            int col = 16 * nn + cl;   // dv
            float bb = B[col];
            ushort4 o;
            o.x = f2bf(acc[nn][0] + bb);
            o.y = f2bf(acc[nn][1] + bb);
            o.z = f2bf(acc[nn][2] + bb);
            o.w = f2bf(acc[nn][3] + bb);
            *reinterpret_cast<ushort4*>(
                vo + ((size_t)h * 64 + col) * SQ + s0 + 16 * w + q4 * 4) = o;
        }
    }
}

// ---------------------------------------------------------------------------
// Kernel 2: flash attention, bf16 MFMA, no online max, KV-split x4
// (R4 version). grid (32, 8, 4). Emits unnormalized partial O + row-sum l.
// ---------------------------------------------------------------------------
#define PW 72

__global__ __launch_bounds__(256) void attn_fwd(
    const unsigned short* __restrict__ qbf,   // [h][2048][64], *0.125 folded
    const unsigned short* __restrict__ kbf,   // [h][2048][64]
    const unsigned short* __restrict__ vbf,   // [h][64][2048] transposed
    float* __restrict__ Opart,                // [z*8+h][2048][64]
    float* __restrict__ lpart)                // [z*8+h][2048]
{
    const int h = blockIdx.y, s0 = blockIdx.x * 64, z = blockIdx.z;
    const int tid = threadIdx.x;
    const int w = tid >> 6, lane = tid & 63, cl = lane & 15, q4 = lane >> 4;
    const int NT = SQ / 64 / NSPLIT;          // 8 tiles per block
    const int t0 = z * NT;

    __shared__ unsigned short Ks[2][64 * PW];
    __shared__ unsigned short Vs[2][64 * PW];
    __shared__ unsigned short Ps[4][16 * PW];

    bf16x8 aq0 = *reinterpret_cast<const bf16x8*>(
        &qbf[((size_t)h * SQ + s0 + 16 * w + cl) * 64 + q4 * 8]);
    bf16x8 aq1 = *reinterpret_cast<const bf16x8*>(
        &qbf[((size_t)h * SQ + s0 + 16 * w + cl) * 64 + 32 + q4 * 8]);

    const int sr = tid >> 3, sg = tid & 7;

    #pragma unroll
    for (int it = 0; it < 2; it++) {
        int r = sr + 32 * it;
        *reinterpret_cast<float4*>(&Ks[0][r * PW + sg * 8]) =
            *reinterpret_cast<const float4*>(&kbf[((size_t)h * SQ + t0 * 64 + r) * 64 + sg * 8]);
        *reinterpret_cast<float4*>(&Vs[0][r * PW + sg * 8]) =
            *reinterpret_cast<const float4*>(&vbf[((size_t)h * 64 + r) * SQ + t0 * 64 + sg * 8]);
    }

    f32x4 o_acc[4] = {};
    float lsum[4] = {};

    for (int tl = 0; tl < NT; tl++) {
        __syncthreads();
        const int buf = tl & 1;
        const bool more = (tl + 1 < NT);
        float4 kr[2], vr[2];
        if (more) {
            #pragma unroll
            for (int it = 0; it < 2; it++) {
                int r = sr + 32 * it;
                kr[it] = *reinterpret_cast<const float4*>(
                    &kbf[((size_t)h * SQ + (t0 + tl + 1) * 64 + r) * 64 + sg * 8]);
                vr[it] = *reinterpret_cast<const float4*>(
                    &vbf[((size_t)h * 64 + r) * SQ + (t0 + tl + 1) * 64 + sg * 8]);
            }
        }

        // ---- S = Q K^T ----
        f32x4 s_acc[4] = {};
        #pragma unroll
        for (int nn = 0; nn < 4; nn++) {
            bf16x8 b0 = *reinterpret_cast<const bf16x8*>(&Ks[buf][(16 * nn + cl) * PW + q4 * 8]);
            bf16x8 b1 = *reinterpret_cast<const bf16x8*>(&Ks[buf][(16 * nn + cl) * PW + 32 + q4 * 8]);
            s_acc[nn] = __builtin_amdgcn_mfma_f32_16x16x32_bf16(aq0, b0, s_acc[nn], 0, 0, 0);
            s_acc[nn] = __builtin_amdgcn_mfma_f32_16x16x32_bf16(aq1, b1, s_acc[nn], 0, 0, 0);
        }

        // ---- p = exp(s), partial row sums, repack for A-operand ----
        #pragma unroll
        for (int r = 0; r < 4; r++) {
            #pragma unroll
            for (int nn = 0; nn < 4; nn++) {
                float pv = __expf(s_acc[nn][r]);
                lsum[r] += pv;
                Ps[w][(q4 * 4 + r) * PW + 16 * nn + cl] = f2bf_trunc(pv);
            }
        }
        bf16x8 ap0 = *reinterpret_cast<const bf16x8*>(&Ps[w][cl * PW + q4 * 8]);
        bf16x8 ap1 = *reinterpret_cast<const bf16x8*>(&Ps[w][cl * PW + 32 + q4 * 8]);

        // ---- O += P V ----
        #pragma unroll
        for (int nn = 0; nn < 4; nn++) {
            bf16x8 b0 = *reinterpret_cast<const bf16x8*>(&Vs[buf][(16 * nn + cl) * PW + q4 * 8]);
            bf16x8 b1 = *reinterpret_cast<const bf16x8*>(&Vs[buf][(16 * nn + cl) * PW + 32 + q4 * 8]);
            o_acc[nn] = __builtin_amdgcn_mfma_f32_16x16x32_bf16(ap0, b0, o_acc[nn], 0, 0, 0);
            o_acc[nn] = __builtin_amdgcn_mfma_f32_16x16x32_bf16(ap1, b1, o_acc[nn], 0, 0, 0);
        }

        if (more) {
            const int nbuf = buf ^ 1;
            #pragma unroll
            for (int it = 0; it < 2; it++) {
                int r = sr + 32 * it;
                *reinterpret_cast<float4*>(&Ks[nbuf][r * PW + sg * 8]) = kr[it];
                *reinterpret_cast<float4*>(&Vs[nbuf][r * PW + sg * 8]) = vr[it];
            }
        }
    }

    #pragma unroll
    for (int r = 0; r < 4; r++) {
        float v = lsum[r];
        #pragma unroll
        for (int off = 1; off < 16; off <<= 1) v += __shfl_xor(v, off);
        lsum[r] = v;
    }

    const size_t zb = (size_t)(z * NH + h);
    if (cl == 0) {
        #pragma unroll
        for (int r = 0; r < 4; r++)
            lpart[zb * SQ + s0 + 16 * w + q4 * 4 + r] = lsum[r];
    }
    #pragma unroll
    for (int nn = 0; nn < 4; nn++)
        #pragma unroll
        for (int r = 0; r < 4; r++)
            Opart[(zb * SQ + s0 + 16 * w + q4 * 4 + r) * 64 + 16 * nn + cl] = o_acc[nn][r];
}

// ---------------------------------------------------------------------------
// Kernel 3: output projection with FUSED split-combine (R5 version): A-tile
// staged by summing 4 z-partials + normalizing inline, plain bf16 MFMA.
// grid (32 s, 8 n), block 256.
// ---------------------------------------------------------------------------
__global__ __launch_bounds__(256) void out_proj(
    const float* __restrict__ Opart, const float* __restrict__ lpart,
    const unsigned short* __restrict__ Wot,
    const float* __restrict__ bo, float* __restrict__ out)
{
    const int s0 = blockIdx.x * 64, n0 = blockIdx.y * 64;
    const int tid = threadIdx.x;
    const int w = tid >> 6, lane = tid & 63, cl = lane & 15, q4 = lane >> 4;
    const int sr = tid >> 3, sg = tid & 7;

    __shared__ unsigned short As[2][64 * 72];
    __shared__ unsigned short Bs[2][64 * 72];
    __shared__ float invL[512];   // [h][s_local]

    #pragma unroll
    for (int k = 0; k < 2; k++) {
        int idx = tid * 2 + k;                    // h*64 + s_local
        int hh = idx >> 6, ss = idx & 63;
        float l = 0.f;
        #pragma unroll
        for (int z = 0; z < NSPLIT; z++)
            l += lpart[(size_t)(z * 8 + hh) * SQ + s0 + ss];
        invL[idx] = 1.0f / l;
    }
    __syncthreads();

    // stage chunk 0 (= head 0)
    #pragma unroll
    for (int it = 0; it < 2; it++) {
        int r = sr + 32 * it;
        float o[8] = {};
        #pragma unroll
        for (int z = 0; z < NSPLIT; z++) {
            const float4* pp = reinterpret_cast<const float4*>(
                &Opart[((size_t)(z * 8) * SQ + s0 + r) * 64 + sg * 8]);
            float4 a = pp[0], b = pp[1];
            o[0] += a.x; o[1] += a.y; o[2] += a.z; o[3] += a.w;
            o[4] += b.x; o[5] += b.y; o[6] += b.z; o[7] += b.w;
        }
        float il = invL[r];
        us8 pk;
        #pragma unroll
        for (int i = 0; i < 8; i++) pk[i] = f2bf(o[i] * il);
        *reinterpret_cast<us8*>(&As[0][r * 72 + sg * 8]) = pk;
        *reinterpret_cast<float4*>(&Bs[0][r * 72 + sg * 8]) =
            *reinterpret_cast<const float4*>(&Wot[(size_t)(n0 + r) * 512 + sg * 8]);
    }

    f32x4 acc[4] = {};

    for (int c = 0; c < 8; c++) {
        __syncthreads();
        const int buf = c & 1;
        const bool more = (c + 1 < 8);
        float4 pre[2][NSPLIT][2];
        float4 wr[2];
        if (more) {
            const int hn = c + 1;
            #pragma unroll
            for (int it = 0; it < 2; it++) {
                int r = sr + 32 * it;
                #pragma unroll
                for (int z = 0; z < NSPLIT; z++) {
                    const float4* pp = reinterpret_cast<const float4*>(
                        &Opart[((size_t)(z * 8 + hn) * SQ + s0 + r) * 64 + sg * 8]);
                    pre[it][z][0] = pp[0];
                    pre[it][z][1] = pp[1];
                }
                wr[it] = *reinterpret_cast<const float4*>(
                    &Wot[(size_t)(n0 + r) * 512 + hn * 64 + sg * 8]);
            }
        }

        bf16x8 a0 = *reinterpret_cast<const bf16x8*>(&As[buf][(16 * w + cl) * 72 + q4 * 8]);
        bf16x8 a1 = *reinterpret_cast<const bf16x8*>(&As[buf][(16 * w + cl) * 72 + 32 + q4 * 8]);
        #pragma unroll
        for (int nn = 0; nn < 4; nn++) {
            bf16x8 b0 = *reinterpret_cast<const bf16x8*>(&Bs[buf][(16 * nn + cl) * 72 + q4 * 8]);
            bf16x8 b1 = *reinterpret_cast<const bf16x8*>(&Bs[buf][(16 * nn + cl) * 72 + 32 + q4 * 8]);
            acc[nn] = __builtin_amdgcn_mfma_f32_16x16x32_bf16(a0, b0, acc[nn], 0, 0, 0);
            acc[nn] = __builtin_amdgcn_mfma_f32_16x16x32_bf16(a1, b1, acc[nn], 0, 0, 0);
        }

        if (more) {
            const int nbuf = buf ^ 1;
            const int hn = c + 1;
            #pragma unroll
            for (int it = 0; it < 2; it++) {
                int r = sr + 32 * it;
                float o[8] = {};
                #pragma unroll
                for (int z = 0; z < NSPLIT; z++) {
                    float4 a = pre[it][z][0], b = pre[it][z][1];
                    o[0] += a.x; o[1] += a.y; o[2] += a.z; o[3] += a.w;
                    o[4] += b.x; o[5] += b.y; o[6] += b.z; o[7] += b.w;
                }
                float il = invL[hn * 64 + r];
                us8 pk;
                #pragma unroll
                for (int i = 0; i < 8; i++) pk[i] = f2bf(o[i] * il);
                *reinterpret_cast<us8*>(&As[nbuf][r * 72 + sg * 8]) = pk;
                *reinterpret_cast<float4*>(&Bs[nbuf][r * 72 + sg * 8]) = wr[it];
            }
        }
    }

    #pragma unroll
    for (int nn = 0; nn < 4; nn++) {
        int col = n0 + 16 * nn + cl;
        float bb = bo[col];
        #pragma unroll
        for (int r = 0; r < 4; r++)
            out[(size_t)(s0 + 16 * w + q4 * 4 + r) * DM + col] = acc[nn][r] + bb;
    }
}

extern "C" void kernel_launch(void* const* d_in, const int* in_sizes, int n_in,
                              void* d_out, int out_size, void* d_ws, size_t ws_size,
                              hipStream_t stream) {
    const float* emb = (const float*)d_in[0];
    const float* Kin = (const float*)d_in[1];
    const float* Vin = (const float*)d_in[2];
    const float* Wq  = (const float*)d_in[3];
    const float* bq  = (const float*)d_in[4];
    const float* Wk  = (const float*)d_in[5];
    const float* bk  = (const float*)d_in[6];
    const float* Wv  = (const float*)d_in[7];
    const float* bv  = (const float*)d_in[8];
    const float* Wo  = (const float*)d_in[9];
    const float* bo  = (const float*)d_in[10];
    float* out = (float*)d_out;

    unsigned short* p = (unsigned short*)d_ws;
    unsigned short* xe  = p; p += (size_t)SQ * DM;
    unsigned short* xk  = p; p += (size_t)SQ * DM;
    unsigned short* xv  = p; p += (size_t)SQ * DM;
    unsigned short* Wt  = p; p += (size_t)24 * 64 * 512;
    unsigned short* Wot = p; p += (size_t)512 * 512;
    unsigned short* qbf = p; p += (size_t)NH * SQ * 64;
    unsigned short* kbf = p; p += (size_t)NH * SQ * 64;
    unsigned short* vbf = p; p += (size_t)NH * SQ * 64;
    float* Opart = (float*)p;                                // 16 MB
    float* lpart = Opart + (size_t)NSPLIT * NH * SQ * 64;    // 256 KB

    convert_all<<<1792, 256, 0, stream>>>(emb, Kin, Vin, Wq, Wk, Wv, Wo,
                                          xe, xk, xv, Wt, Wot);
    qkv_mfma<<<dim3(32, 8, 3), 256, 0, stream>>>(xe, xk, xv, Wt, bq, bk, bv,
                                                 qbf, kbf, vbf);
    attn_fwd<<<dim3(32, 8, NSPLIT), 256, 0, stream>>>(qbf, kbf, vbf, Opart, lpart);
    out_proj<<<dim3(32, 8), 256, 0, stream>>>(Opart, lpart, Wot, bo, out);
}